// Round 12
// baseline (26.631 us; speedup 1.0000x reference)
//
#include <hip/hip_runtime.h>
#include <hip/hip_bf16.h>
#include <cstdint>

// VQ-VAE vector quantize: N=65536 vectors, D=64, K=512 codes.
// d_in[0]: inputs fp32 [65536,64], d_in[1]: embeddings fp32 [512,64]
// d_out: [0]=loss, [1..4194304]=latent (gathered fp32 embeddings)
//
// R12: 2 kernels. No setup kernel: each wave builds its 128-code B-slice
// (bf16(-e), MFMA fragment order) directly from emb into VGPRs and computes
// 0.5*||e||^2 in-register (shfl_xor butterfly over the 4 lanes holding each
// code). Grid 512 x 128 rows. Row-major coalesced epilogue. Loss from the
// winning packed distance; separate 1-block deterministic reduce.

typedef __attribute__((ext_vector_type(8))) short bf16x8;
typedef __attribute__((ext_vector_type(4))) float f32x4;

__device__ __forceinline__ short f2bf(float f) {
    uint32_t u = __builtin_bit_cast(uint32_t, f);
    u += 0x7FFFu + ((u >> 16) & 1u);   // round-to-nearest-even
    return (short)(u >> 16);
}

__device__ __forceinline__ float sumsq4(float4 v, float acc) {
    return fmaf(v.x, v.x, fmaf(v.y, v.y, fmaf(v.z, v.z, fmaf(v.w, v.w, acc))));
}

__device__ __forceinline__ bf16x8 packneg(float4 a, float4 b) {
    bf16x8 f;
    f[0] = f2bf(-a.x); f[1] = f2bf(-a.y); f[2] = f2bf(-a.z); f[3] = f2bf(-a.w);
    f[4] = f2bf(-b.x); f[5] = f2bf(-b.y); f[6] = f2bf(-b.z); f[7] = f2bf(-b.w);
    return f;
}

__device__ __forceinline__ bf16x8 packpos(float4 a, float4 b) {
    bf16x8 f;
    f[0] = f2bf(a.x); f[1] = f2bf(a.y); f[2] = f2bf(a.z); f[3] = f2bf(a.w);
    f[4] = f2bf(b.x); f[5] = f2bf(b.y); f[6] = f2bf(b.z); f[7] = f2bf(b.w);
    return f;
}

// ---------------- Kernel 1: main (512 blocks x 256) ----------------
// Block owns 128 rows (8 row-tiles). Wave w holds codes [w*128, w*128+128)
// in VGPRs; computes its partial packed-argmin for all 128 rows; combine
// across waves via LDS; row-major coalesced epilogue.
__global__ __launch_bounds__(256)
void vq_main(const float* __restrict__ flat, const float* __restrict__ emb,
             float* __restrict__ partials, float* __restrict__ out) {
    __shared__ bf16x8 albuf[8][2][64];   // 16 KB  [slot][ks][lane] A fragments
    __shared__ float  cmb[4][128];       // 2 KB   [wave][row] packed partial min
    __shared__ float  red[4];

    const int tid = threadIdx.x, bid = blockIdx.x;
    const int lane = tid & 63, wid = tid >> 6;
    const int cb = lane & 15, g = lane >> 4;
    const int rb = bid * 128;
    const char* dummy = nullptr; (void)dummy;

    // ---- A loads: wave's own 32 rows (2 groups of 16), 8 float4 from HBM ----
    float4 ar[2][2][2];
    #pragma unroll
    for (int it = 0; it < 2; ++it) {
        const float* asrc = flat + (long)(rb + it * 64 + wid * 16 + cb) * 64 + g * 8;
        ar[it][0][0] = *(const float4*)(asrc);
        ar[it][0][1] = *(const float4*)(asrc + 4);
        ar[it][1][0] = *(const float4*)(asrc + 32);
        ar[it][1][1] = *(const float4*)(asrc + 36);
    }

    // ---- B slice: build bf16(-e) fragments + norms from emb directly ----
    bf16x8 bv[8][2];
    float hvv[8];
    #pragma unroll
    for (int c = 0; c < 8; ++c) {
        const int code = ((wid * 8 + c) << 4) | cb;
        const float* es = emb + code * 64 + g * 8;
        float4 v0 = *(const float4*)(es);
        float4 v1 = *(const float4*)(es + 4);
        float4 w0 = *(const float4*)(es + 32);
        float4 w1 = *(const float4*)(es + 36);
        float n = sumsq4(v0, 0.f); n = sumsq4(v1, n);
        n = sumsq4(w0, n);         n = sumsq4(w1, n);
        hvv[c] = n;                       // partial: this lane's 16 dims
        bv[c][0] = packneg(v0, v1);
        bv[c][1] = packneg(w0, w1);
    }
    // butterfly over the 4 lanes (g=0..3) holding each code's 64 dims
    #pragma unroll
    for (int c = 0; c < 8; ++c) {
        float n = hvv[c];
        n += __shfl_xor(n, 16, 64);
        n += __shfl_xor(n, 32, 64);
        hvv[c] = 0.5f * n;                // 0.5*||e||^2, full
    }

    // ---- ||x||^2 partial + A fragments -> LDS ----
    float xx = 0.f;
    #pragma unroll
    for (int it = 0; it < 2; ++it) {
        #pragma unroll
        for (int ks = 0; ks < 2; ++ks) {
            xx = sumsq4(ar[it][ks][0], xx);
            xx = sumsq4(ar[it][ks][1], xx);
        }
        albuf[it * 4 + wid][0][lane] = packpos(ar[it][0][0], ar[it][0][1]);
        albuf[it * 4 + wid][1][lane] = packpos(ar[it][1][0], ar[it][1][1]);
    }
    __syncthreads();

    // ---- compute: 8 row-tiles x 8 code-tiles, B from VGPRs ----
    float pm[8][4];
    #pragma unroll
    for (int rt = 0; rt < 8; ++rt)
        #pragma unroll
        for (int j = 0; j < 4; ++j) pm[rt][j] = __builtin_bit_cast(float, 0x7F800000u);

    #pragma unroll
    for (int rt = 0; rt < 8; ++rt) {
        bf16x8 a0 = albuf[rt][0][lane];
        bf16x8 a1 = albuf[rt][1][lane];
        #pragma unroll
        for (int c = 0; c < 8; ++c) {
            const int colv = ((wid * 8 + c) << 4) | cb;
            const float h = hvv[c];
            f32x4 acc = {h, h, h, h};     // 0.5||e||^2 - x.e   (B = -e)
            acc = __builtin_amdgcn_mfma_f32_16x16x32_bf16(a0, bv[c][0], acc, 0, 0, 0);
            acc = __builtin_amdgcn_mfma_f32_16x16x32_bf16(a1, bv[c][1], acc, 0, 0, 0);
            #pragma unroll
            for (int j = 0; j < 4; ++j) {
                uint32_t dp = (__builtin_bit_cast(uint32_t, acc[j]) & 0xFFFFFE00u) | (uint32_t)colv;
                pm[rt][j] = fminf(pm[rt][j], __builtin_bit_cast(float, dp));
            }
        }
    }

    // ---- butterfly min over the 16 column-class lanes ----
    #pragma unroll
    for (int m = 1; m < 16; m <<= 1) {
        #pragma unroll
        for (int rt = 0; rt < 8; ++rt)
            #pragma unroll
            for (int j = 0; j < 4; ++j)
                pm[rt][j] = fminf(pm[rt][j], __shfl_xor(pm[rt][j], m, 64));
    }
    // wave's partial winner for block-row (rt>>2)*64 + (rt&3)*16 + g*4 + j
    if (cb == 0) {
        #pragma unroll
        for (int rt = 0; rt < 8; ++rt) {
            const int base = (rt >> 2) * 64 + (rt & 3) * 16;
            #pragma unroll
            for (int j = 0; j < 4; ++j)
                cmb[wid][base + g * 4 + j] = pm[rt][j];
        }
    }
    __syncthreads();

    // ---- epilogue: wave w streams rows [w*32, w*32+32), fully coalesced ----
    float dacc = 0.f;   // sum of winning packed distances (identical per lane)
    float* ob = out + 1 + (long)(rb + wid * 32) * 64;
    #pragma unroll 4
    for (int r = 0; r < 32; ++r) {
        const int row = wid * 32 + r;
        float mn = fminf(fminf(cmb[0][row], cmb[1][row]),
                         fminf(cmb[2][row], cmb[3][row]));
        const uint32_t mb = __builtin_bit_cast(uint32_t, mn);
        dacc += __builtin_bit_cast(float, mb & 0xFFFFFE00u);
        ob[r * 64 + lane] = emb[(int)(mb & 0x1FFu) * 64 + lane];
    }

    // ---- loss partial: waveSum(xx) + 2 * sum(winning dist') ----
    float t = xx;
    #pragma unroll
    for (int m = 32; m; m >>= 1) t += __shfl_down(t, m, 64);
    if (lane == 0) red[wid] = fmaf(2.f, dacc, t);
    __syncthreads();
    if (tid == 0) partials[bid] = red[0] + red[1] + red[2] + red[3];
}

// ---------------- Kernel 2: deterministic final reduce (1 block) ----------------
__global__ __launch_bounds__(256)
void vq_loss(const float* __restrict__ partials, float* __restrict__ out) {
    __shared__ float red[4];
    const int tid = threadIdx.x;
    float acc = partials[tid] + partials[tid + 256];
    #pragma unroll
    for (int m = 32; m; m >>= 1) acc += __shfl_down(acc, m, 64);
    if ((tid & 63) == 0) red[tid >> 6] = acc;
    __syncthreads();
    // loss = 0.25*e_loss + q_loss = 1.25 * mse (forward)
    if (tid == 0) out[0] = 1.25f * (red[0] + red[1] + red[2] + red[3]) / 4194304.0f;
}

extern "C" void kernel_launch(void* const* d_in, const int* in_sizes, int n_in,
                              void* d_out, int out_size, void* d_ws, size_t ws_size,
                              hipStream_t stream) {
    const float* flat = (const float*)d_in[0];   // [65536,64]
    const float* emb  = (const float*)d_in[1];   // [512,64]
    float* out = (float*)d_out;
    float* partials = (float*)d_ws;              // 512 floats

    vq_main<<<512, 256, 0, stream>>>(flat, emb, partials, out);
    vq_loss<<<1, 256, 0, stream>>>(partials, out);
}